// Round 9
// baseline (1145.967 us; speedup 1.0000x reference)
//
#include <hip/hip_runtime.h>

typedef unsigned short u16;
typedef short bf16x8 __attribute__((ext_vector_type(8)));
typedef float f32x16 __attribute__((ext_vector_type(16)));
typedef unsigned short u16x4v __attribute__((ext_vector_type(4)));
typedef unsigned short u16x8v __attribute__((ext_vector_type(8)));

#define LN_EPS 1e-5f

__device__ __forceinline__ u16 f2bf(float v) {
    unsigned x = __float_as_uint(v);
    x += 0x7fffu + ((x >> 16) & 1u);        // RNE to bf16
    return (u16)(x >> 16);
}
__device__ __forceinline__ float bf2f(u16 u) {
    return __uint_as_float(((unsigned)u) << 16);
}

#define GLD16(gp, lp) __builtin_amdgcn_global_load_lds( \
    (const __attribute__((address_space(1))) void*)(gp), \
    (__attribute__((address_space(3))) void*)(lp), 16, 0, 0)

// ---------------------------------------------------------------------------
// fp32 [R][DIN] row-major -> hi/lo bf16 planes, MFMA-staging layout
// [DIN/8][R][8]. Used for WEIGHTS only (tiny).
// ---------------------------------------------------------------------------
__global__ __launch_bounds__(256)
void swizzle_split(const float* __restrict__ src, u16* __restrict__ hi,
                   u16* __restrict__ lo, int R, int DIN)
{
    __shared__ __align__(16) u16 SH[2][24][17][8];   // [plane][kc][row(pad)][8]
    const int tid  = threadIdx.x;
    const int row0 = blockIdx.x * 16;
    const int QK   = DIN / 16;          // float4 slots per row per quarter
    const int kq0  = QK * blockIdx.y;   // float4 offset of this quarter
    const int NKC  = DIN / 32;          // 16B k-chunks per quarter (<=24)

    const int slots = 16 * QK;
    for (int s = tid; s < slots; s += 256) {
        int row = s / QK, kq = s % QK;
        float4 v = *(const float4*)(src + (long)(row0 + row) * DIN + (long)(kq0 + kq) * 4);
        int kc = kq >> 1, jh = (kq & 1) * 4;
        float vv[4] = {v.x, v.y, v.z, v.w};
        u16x4v h, l;
#pragma unroll
        for (int j = 0; j < 4; ++j) {
            u16 hb = f2bf(vv[j]);
            h[j] = hb;
            l[j] = f2bf(vv[j] - bf2f(hb));
        }
        *(u16x4v*)(&SH[0][kc][row][jh]) = h;
        *(u16x4v*)(&SH[1][kc][row][jh]) = l;
    }
    __syncthreads();
    const int chunks = NKC * 16;
    for (int s = tid; s < chunks; s += 256) {
        int row = s & 15, kc = s >> 4;
        long o = ((long)(kq0 / 2 + kc) * R + row0 + row) * 8;
        *(u16x8v*)(hi + o) = *(const u16x8v*)(&SH[0][kc][row][0]);
        *(u16x8v*)(lo + o) = *(const u16x8v*)(&SH[1][kc][row][0]);
    }
}

// ---------------------------------------------------------------------------
// Shared epilogue: bias + LayerNorm + affine + relu, then store.
// OUT_MODE: 1 = split hi/lo bf16 swizzled global, 2 = LDS tile [64][129].
// C/D layout: col=lane&31, row=(reg&3)+8*(reg>>2)+4*(lane>>5)  [m74/m101].
// ---------------------------------------------------------------------------
template<int DOUT, int OUT_MODE, int NT>
__device__ __forceinline__ void ln_epilogue(
    f32x16 (&acc)[2][NT], float (&lnp)[4][64][2],
    const float* __restrict__ bias, const float* __restrict__ gam,
    const float* __restrict__ bet,
    u16* __restrict__ Yh, u16* __restrict__ Yl, float* __restrict__ Yf,
    float* __restrict__ Hlds,
    long row0, int NR, int wv, int l31, int hh)
{
    float gg[NT], bb[NT], bev[NT];
#pragma unroll
    for (int u = 0; u < NT; ++u) {
        int c = wv * (DOUT / 4) + u * 32 + l31;
        bb[u] = bias[c]; gg[u] = gam[c]; bev[u] = bet[c];
    }
#pragma unroll
    for (int t = 0; t < 2; ++t)
#pragma unroll
        for (int r = 0; r < 16; ++r) {
            float s1 = 0.f, s2 = 0.f;
#pragma unroll
            for (int u = 0; u < NT; ++u) {
                float v = acc[t][u][r] + bb[u];
                acc[t][u][r] = v;
                s1 += v; s2 += v * v;
            }
#pragma unroll
            for (int off = 1; off < 32; off <<= 1) {
                s1 += __shfl_xor(s1, off, 64);
                s2 += __shfl_xor(s2, off, 64);
            }
            int row = t * 32 + (r & 3) + 8 * (r >> 2) + 4 * hh;
            if (l31 == r) { lnp[wv][row][0] = s1; lnp[wv][row][1] = s2; }
        }
    __syncthreads();
#pragma unroll
    for (int t = 0; t < 2; ++t)
#pragma unroll
        for (int r = 0; r < 16; ++r) {
            int row = t * 32 + (r & 3) + 8 * (r >> 2) + 4 * hh;
            float s1 = lnp[0][row][0] + lnp[1][row][0] + lnp[2][row][0] + lnp[3][row][0];
            float s2 = lnp[0][row][1] + lnp[1][row][1] + lnp[2][row][1] + lnp[3][row][1];
            float mean = s1 * (1.f / DOUT);
            float inv  = rsqrtf(s2 * (1.f / DOUT) - mean * mean + LN_EPS);
            long gr = row0 + row;
#pragma unroll
            for (int u = 0; u < NT; ++u) {
                int c = wv * (DOUT / 4) + u * 32 + l31;
                float v = (acc[t][u][r] - mean) * inv * gg[u] + bev[u];
                v = fmaxf(v, 0.f);
                if constexpr (OUT_MODE == 1) {
                    u16 hv = f2bf(v);
                    long o = ((long)(c >> 3) * NR + gr) * 8 + (c & 7);
                    Yh[o] = hv;
                    Yl[o] = f2bf(v - bf2f(hv));
                } else if constexpr (OUT_MODE == 2) {
                    Hlds[row * 129 + c] = v;
                } else {
                    Yf[gr * DOUT + c] = v;
                }
            }
        }
}

// ---------------------------------------------------------------------------
// W-fragment load (next k-step) and MFMA consume (current k-step).
// Pipeline is FORCED with sched_barrier(0): the compiler may not sink the
// loads back to their use (round-5/8 showed it collapses a plain source
// double-buffer: VGPR stayed 76). Fence after each ldwf =>
// region [mfma_use(cur), ldwf(next)]: loads issue under the MFMA cluster,
// wait at next use becomes a counted vmcnt, never a drain (T4).
// ---------------------------------------------------------------------------
template<int NT>
__device__ __forceinline__ void ldwf(const u16*& wph, const u16*& wpl,
                                     long wstep, bf16x8 (&wf)[NT][2])
{
#pragma unroll
    for (int u = 0; u < NT; ++u) {
        wf[u][0] = *(const bf16x8*)(wph + u * 256);
        wf[u][1] = *(const bf16x8*)(wpl + u * 256);
    }
    wph += wstep; wpl += wstep;
}

// chain-position-outer: 8 independent acc chains between dependent uses;
// per-acc order unchanged -> bit-identical numerics.
template<int NT>
__device__ __forceinline__ void mfma_use(
    const bf16x8 (&wf)[NT][2],
    const u16* AL0, const u16* AL1,   // chunk=hh base for plane0/plane1
    f32x16 (&acc)[2][NT], int l31)
{
    bf16x8 af[2][2];
#pragma unroll
    for (int t = 0; t < 2; ++t) {
        af[t][0] = *(const bf16x8*)(AL0 + (t * 32 + l31) * 8);
        af[t][1] = *(const bf16x8*)(AL1 + (t * 32 + l31) * 8);
    }
#pragma unroll
    for (int t = 0; t < 2; ++t)
#pragma unroll
        for (int u = 0; u < NT; ++u)
            acc[t][u] = __builtin_amdgcn_mfma_f32_32x32x16_bf16(af[t][0], wf[u][0], acc[t][u], 0, 0, 0);
#pragma unroll
    for (int t = 0; t < 2; ++t)
#pragma unroll
        for (int u = 0; u < NT; ++u)
            acc[t][u] = __builtin_amdgcn_mfma_f32_32x32x16_bf16(af[t][0], wf[u][1], acc[t][u], 0, 0, 0);
#pragma unroll
    for (int t = 0; t < 2; ++t)
#pragma unroll
        for (int u = 0; u < NT; ++u)
            acc[t][u] = __builtin_amdgcn_mfma_f32_32x32x16_bf16(af[t][1], wf[u][0], acc[t][u], 0, 0, 0);
}

#define SB0 __builtin_amdgcn_sched_barrier(0)

// 4 pipelined s-steps of one slab. Last ldwf prefetches next slab's step 0
// across the barrier (barrier drain then covers its latency once per slab).
// Final slab's prefetch overreads <=16 KB past W end (slack allocated).
#define SLAB_PHASES(CB)                                                        \
    ldwf<NT>(wph, wpl, wstep, wfb); SB0;                                       \
    mfma_use<NT>(wfa, &AL[CB][0][0][hh][0], &AL[CB][0][1][hh][0], acc, l31);   \
    ldwf<NT>(wph, wpl, wstep, wfa); SB0;                                       \
    mfma_use<NT>(wfb, &AL[CB][1][0][hh][0], &AL[CB][1][1][hh][0], acc, l31);   \
    ldwf<NT>(wph, wpl, wstep, wfb); SB0;                                       \
    mfma_use<NT>(wfa, &AL[CB][2][0][hh][0], &AL[CB][2][1][hh][0], acc, l31);   \
    ldwf<NT>(wph, wpl, wstep, wfa); SB0;                                       \
    mfma_use<NT>(wfb, &AL[CB][3][0][hh][0], &AL[CB][3][1][hh][0], acc, l31);

// ---------------------------------------------------------------------------
// Layer 1, 64-row blocks (r64): fp32 X input, fused split staging
// (16 fp32/thread), forced W-fragment register double-buffer.
// ---------------------------------------------------------------------------
template<int DOUT>
__global__ __launch_bounds__(256, 2)
void mfma_layer1(const float* __restrict__ X,
                 const u16* __restrict__ Wh, const u16* __restrict__ Wl,
                 const float* __restrict__ bias, const float* __restrict__ gam,
                 const float* __restrict__ bet,
                 u16* __restrict__ Yh, u16* __restrict__ Yl,
                 int DIN, int NR, long rbase)
{
    constexpr int NT = DOUT / 128;
    __shared__ __align__(16) u16 AL[2][4][2][2][520]; // [buf][step][plane][chunk][pad]
    __shared__ float lnp[4][64][2];

    const int tid  = threadIdx.x;
    const int lane = tid & 63, wv = tid >> 6;
    const int l31  = lane & 31, hh = lane >> 5;
    const long lrow0 = (long)blockIdx.x * 64;
    const long row0  = rbase + lrow0;

    const int srow  = wv * 16 + (lane >> 2);       // staging row this thread owns
    const int kpart = lane & 3;                    // which 16-k step it stages
    const float* xp = X + (lrow0 + srow) * DIN + kpart * 16;

    const u16* wph = Wh + ((long)hh * DOUT + wv * (DOUT / 4) + l31) * 8;
    const u16* wpl = Wl + ((long)hh * DOUT + wv * (DOUT / 4) + l31) * 8;
    const long wstep = (long)2 * DOUT * 8;

    f32x16 acc[2][NT];
#pragma unroll
    for (int t = 0; t < 2; ++t)
#pragma unroll
        for (int u = 0; u < NT; ++u)
#pragma unroll
            for (int e = 0; e < 16; ++e) acc[t][u][e] = 0.f;

    const int nslab = DIN / 64;

    auto stage = [&](const float* p, int buf) {
#pragma unroll
        for (int c = 0; c < 2; ++c) {
            float4 v0 = *(const float4*)(p + c * 8);
            float4 v1 = *(const float4*)(p + c * 8 + 4);
            float f[8] = {v0.x, v0.y, v0.z, v0.w, v1.x, v1.y, v1.z, v1.w};
            u16x8v h, l;
#pragma unroll
            for (int j = 0; j < 8; ++j) {
                u16 hb = f2bf(f[j]);
                h[j] = hb;
                l[j] = f2bf(f[j] - bf2f(hb));
            }
            *(u16x8v*)(&AL[buf][kpart][0][c][srow * 8]) = h;
            *(u16x8v*)(&AL[buf][kpart][1][c][srow * 8]) = l;
        }
    };

    bf16x8 wfa[NT][2], wfb[NT][2];
    ldwf<NT>(wph, wpl, wstep, wfa);                // slab 0, step 0

    stage(xp, 0);                                   // prologue: slab 0
    for (int sl = 0; sl < nslab; ++sl) {
        __syncthreads();
        const int cb = sl & 1;
        if (sl + 1 < nslab) stage(xp + (sl + 1) * 64, cb ^ 1);
        SLAB_PHASES(cb)
    }

    ln_epilogue<DOUT, 1, NT>(acc, lnp, bias, gam, bet, Yh, Yl, nullptr, nullptr,
                             row0, NR, wv, l31, hh);
}

// ---------------------------------------------------------------------------
// Layers 2/3, 64-row blocks (r64): pre-swizzled hi/lo bf16 A via GLD16 slab
// double-buffer; forced W-fragment register double-buffer.
// OUT_MODE==2 fuses layer 4 via the Hs LDS tile (no h3 HBM round trip).
// ---------------------------------------------------------------------------
template<int DOUT, int OUT_MODE>
__global__ __launch_bounds__(256, 2)
void mfma_layer(const u16* __restrict__ Ah, const u16* __restrict__ Al,
                const u16* __restrict__ Wh, const u16* __restrict__ Wl,
                const float* __restrict__ bias, const float* __restrict__ gam,
                const float* __restrict__ bet,
                u16* __restrict__ Yh, u16* __restrict__ Yl,
                float* __restrict__ Yf, int DIN, int NR,
                const float* __restrict__ W4, const float* __restrict__ b4)
{
    constexpr int NT = DOUT / 128;
    __shared__ __align__(16) u16 AL[2][4][2][2][64 * 8];
    __shared__ float lnp[4][64][2];
    // layer-4 fusion tile: [64][129] fp32; stride 129 -> bank=(row+col)%32,
    // conflict-free both directions. 1-elem dummy otherwise.
    __shared__ float Hs[OUT_MODE == 2 ? 64 * 129 : 1];

    const int tid  = threadIdx.x;
    const int lane = tid & 63, wv = tid >> 6;
    const int l31  = lane & 31, hh = lane >> 5;
    const long row0 = (long)blockIdx.x * 64;

    const u16* gpA[4];
    const long stA = (long)8 * NR * 8;
#pragma unroll
    for (int t = 0; t < 4; ++t) {
        int p = t & 1, c = t >> 1;
        const u16* base = p ? Al : Ah;
        gpA[t] = base + ((long)(2 * wv + c) * NR + row0 + lane) * 8;
    }

    const u16* wph = Wh + ((long)hh * DOUT + wv * (DOUT / 4) + l31) * 8;
    const u16* wpl = Wl + ((long)hh * DOUT + wv * (DOUT / 4) + l31) * 8;
    const long wstep = (long)2 * DOUT * 8;

    f32x16 acc[2][NT];
#pragma unroll
    for (int t = 0; t < 2; ++t)
#pragma unroll
        for (int u = 0; u < NT; ++u)
#pragma unroll
            for (int e = 0; e < 16; ++e) acc[t][u][e] = 0.f;

    const int nslab = DIN / 64;

    bf16x8 wfa[NT][2], wfb[NT][2];
    ldwf<NT>(wph, wpl, wstep, wfa);                // slab 0, step 0

#pragma unroll
    for (int t = 0; t < 4; ++t) {
        GLD16(gpA[t], &AL[0][wv][t & 1][t >> 1][0]);
        gpA[t] += stA;
    }

    for (int sl = 0; sl < nslab; ++sl) {
        __syncthreads();
        const int cb = sl & 1;
        if (sl + 1 < nslab) {
#pragma unroll
            for (int t = 0; t < 4; ++t) {
                GLD16(gpA[t], &AL[cb ^ 1][wv][t & 1][t >> 1][0]);
                gpA[t] += stA;
            }
        }
        SLAB_PHASES(cb)
    }

    ln_epilogue<DOUT, OUT_MODE, NT>(acc, lnp, bias, gam, bet, Yh, Yl, Yf, Hs,
                                    row0, NR, wv, l31, hh);

    if constexpr (OUT_MODE == 2) {
        // Fused layer 4: Z[row][o] = H[row][:] . W4[o][:] + b4[o]
        __syncthreads();
        const int rowl = tid & 63;
        const int og   = wv;            // 4 waves x 8 outputs = 32 cols
        float a4[8];
#pragma unroll
        for (int j = 0; j < 8; ++j) a4[j] = 0.f;
        for (int k = 0; k < 128; k += 4) {
            float h0 = Hs[rowl * 129 + k + 0];
            float h1 = Hs[rowl * 129 + k + 1];
            float h2 = Hs[rowl * 129 + k + 2];
            float h3 = Hs[rowl * 129 + k + 3];
#pragma unroll
            for (int j = 0; j < 8; ++j) {
                const float4 w = *(const float4*)(W4 + (og * 8 + j) * 128 + k);
                a4[j] = fmaf(h0, w.x, fmaf(h1, w.y, fmaf(h2, w.z, fmaf(h3, w.w, a4[j]))));
            }
        }
        const long gr = row0 + rowl;
#pragma unroll
        for (int j = 0; j < 8; ++j) Yf[gr * 32 + og * 8 + j] = a4[j] + b4[og * 8 + j];
    }
}

// ---------------------------------------------------------------------------
// Prototypes: one block per class, no atomics.
// ---------------------------------------------------------------------------
__global__ __launch_bounds__(256)
void proto_k(const float* __restrict__ Zs, const int* __restrict__ lab,
             float* __restrict__ P)
{
    const int c = blockIdx.x;
    const int tid = threadIdx.x, lane = tid & 63, wv = tid >> 6;
    float acc[32];
#pragma unroll
    for (int d = 0; d < 32; ++d) acc[d] = 0.f;
    float cnt = 0.f;
    for (int i = tid; i < 32768; i += 256) {
        if (lab[i] == c) {
            cnt += 1.f;
#pragma unroll
            for (int d = 0; d < 32; ++d) acc[d] += Zs[(long)i * 32 + d];
        }
    }
    __shared__ float wsum[4][32];
    __shared__ float wcnt[4];
#pragma unroll
    for (int d = 0; d < 32; ++d) {
        float v = acc[d];
        for (int off = 32; off > 0; off >>= 1) v += __shfl_xor(v, off, 64);
        if (lane == 0) wsum[wv][d] = v;
    }
    {
        float v = cnt;
        for (int off = 32; off > 0; off >>= 1) v += __shfl_xor(v, off, 64);
        if (lane == 0) wcnt[wv] = v;
    }
    __syncthreads();
    if (tid < 32) {
        float s  = wsum[0][tid] + wsum[1][tid] + wsum[2][tid] + wsum[3][tid];
        float cn = wcnt[0] + wcnt[1] + wcnt[2] + wcnt[3];
        P[c * 32 + tid] = s / fmaxf(cn, 1.f);
    }
}

// ---------------------------------------------------------------------------
// -cdist: one thread per query row, protos in LDS.
// ---------------------------------------------------------------------------
__global__ __launch_bounds__(256)
void dist_k(const float* __restrict__ Zq, const float* __restrict__ P,
            float* __restrict__ O)
{
    __shared__ float ps[64 * 32];
    __shared__ float pn[64];
    const int tid = threadIdx.x;
    for (int idx = tid; idx < 2048; idx += 256) ps[idx] = P[idx];
    __syncthreads();
    if (tid < 64) {
        float s = 0.f;
        for (int d = 0; d < 32; ++d) { float v = ps[tid * 32 + d]; s += v * v; }
        pn[tid] = s;
    }
    __syncthreads();

    long q = (long)blockIdx.x * 256 + tid;
    float zr[32];
#pragma unroll
    for (int d = 0; d < 32; d += 4) {
        float4 v = *(const float4*)(Zq + q * 32 + d);
        zr[d] = v.x; zr[d + 1] = v.y; zr[d + 2] = v.z; zr[d + 3] = v.w;
    }
    float zz = 0.f;
#pragma unroll
    for (int d = 0; d < 32; ++d) zz += zr[d] * zr[d];
    for (int p = 0; p < 64; ++p) {
        float dot = 0.f;
#pragma unroll
        for (int d = 0; d < 32; ++d) dot = fmaf(zr[d], ps[p * 32 + d], dot);
        float sq = zz + pn[p] - 2.f * dot;
        O[q * 64 + p] = -sqrtf(fmaxf(sq, 0.f));
    }
}

// ---------------------------------------------------------------------------
// Host side — single pass over all 98304 rows (fits 768 MiB workspace).
// ---------------------------------------------------------------------------
extern "C" void kernel_launch(void* const* d_in, const int* in_sizes, int n_in,
                              void* d_out, int out_size, void* d_ws, size_t ws_size,
                              hipStream_t stream)
{
    const float* supp = (const float*)d_in[0];   // [32768,768]
    const int*   lab  = (const int*)  d_in[1];   // [32768]
    const float* qry  = (const float*)d_in[2];   // [65536,768]
    const float* W1 = (const float*)d_in[3];  const float* b1 = (const float*)d_in[4];
    const float* g1 = (const float*)d_in[5];  const float* be1= (const float*)d_in[6];
    const float* W2 = (const float*)d_in[7];  const float* b2 = (const float*)d_in[8];
    const float* g2 = (const float*)d_in[9];  const float* be2= (const float*)d_in[10];
    const float* W3 = (const float*)d_in[11]; const float* b3 = (const float*)d_in[12];
    const float* g3 = (const float*)d_in[13]; const float* be3= (const float*)d_in[14];
    const float* W4 = (const float*)d_in[15]; const float* b4 = (const float*)d_in[16];
    float* out = (float*)d_out;                  // [65536,64]

    const long NTOT = 98304, NS = 32768, NQ = 65536;
    const int  NR = (int)NTOT;

    char* wsp = (char*)d_ws;
    size_t off = 0;
    auto take = [&](size_t bytes) {
        char* p = wsp + off;
        off += (bytes + 255) & ~(size_t)255;
        return (void*)p;
    };

    float* zAll  = (float*)take((size_t)NTOT * 32 * 4);
    float* proto = (float*)take(2048 * 4);
    // W buffers: +16 KB slack each — the pipelined W prefetch reads one
    // k-step past the end on the final slab (values unused).
    u16* W1h = (u16*)take((size_t)512 * 768 * 2 + 16384);
    u16* W1l = (u16*)take((size_t)512 * 768 * 2 + 16384);
    u16* W2h = (u16*)take((size_t)512 * 512 * 2 + 16384);
    u16* W2l = (u16*)take((size_t)512 * 512 * 2 + 16384);
    u16* W3h = (u16*)take((size_t)128 * 512 * 2 + 16384);
    u16* W3l = (u16*)take((size_t)128 * 512 * 2 + 16384);
    u16* h1h = (u16*)take((size_t)NTOT * 512 * 2);
    u16* h1l = (u16*)take((size_t)NTOT * 512 * 2);
    u16* h2h = (u16*)take((size_t)NTOT * 512 * 2);
    u16* h2l = (u16*)take((size_t)NTOT * 512 * 2);
    // total ~418 MB <= 768 MiB ws

    // split+swizzle weights (tiny)
    swizzle_split<<<dim3(32, 4), dim3(256), 0, stream>>>(W1, W1h, W1l, 512, 768);
    swizzle_split<<<dim3(32, 4), dim3(256), 0, stream>>>(W2, W2h, W2l, 512, 512);
    swizzle_split<<<dim3(8, 4),  dim3(256), 0, stream>>>(W3, W3h, W3l, 128, 512);

    // layer 1: fused fp32->split staging; two dispatches (support, query)
    mfma_layer1<512><<<dim3(NS / 64), dim3(256), 0, stream>>>(
        supp, W1h, W1l, b1, g1, be1, h1h, h1l, 768, NR, 0);
    mfma_layer1<512><<<dim3(NQ / 64), dim3(256), 0, stream>>>(
        qry, W1h, W1l, b1, g1, be1, h1h, h1l, 768, NR, NS);

    mfma_layer<512, 1><<<dim3(NTOT / 64), dim3(256), 0, stream>>>(
        h1h, h1l, W2h, W2l, b2, g2, be2, h2h, h2l, nullptr, 512, NR,
        nullptr, nullptr);
    // layer 3 with fused layer 4: writes zAll directly (no h3 round trip)
    mfma_layer<128, 2><<<dim3(NTOT / 64), dim3(256), 0, stream>>>(
        h2h, h2l, W3h, W3l, b3, g3, be3, nullptr, nullptr, zAll, 512, NR,
        W4, b4);

    proto_k<<<dim3(64),  dim3(256), 0, stream>>>(zAll, lab, proto);
    dist_k<<<dim3(256), dim3(256), 0, stream>>>(zAll + NS * 32, proto, out);
}

// Round 12
// 1091.299 us; speedup vs baseline: 1.0501x; 1.0501x over previous
//
#include <hip/hip_runtime.h>

typedef unsigned short u16;
typedef short bf16x8 __attribute__((ext_vector_type(8)));
typedef float f32x16 __attribute__((ext_vector_type(16)));
typedef unsigned short u16x4v __attribute__((ext_vector_type(4)));
typedef unsigned short u16x8v __attribute__((ext_vector_type(8)));

#define LN_EPS 1e-5f

__device__ __forceinline__ u16 f2bf(float v) {
    unsigned x = __float_as_uint(v);
    x += 0x7fffu + ((x >> 16) & 1u);        // RNE to bf16
    return (u16)(x >> 16);
}
__device__ __forceinline__ float bf2f(u16 u) {
    return __uint_as_float(((unsigned)u) << 16);
}

#define GLD16(gp, lp) __builtin_amdgcn_global_load_lds( \
    (const __attribute__((address_space(1))) void*)(gp), \
    (__attribute__((address_space(3))) void*)(lp), 16, 0, 0)

// ---------------------------------------------------------------------------
// fp32 [R][DIN] row-major -> hi/lo bf16 planes, MFMA-staging layout
// [DIN/8][R][8]. Used for WEIGHTS only (tiny).
// ---------------------------------------------------------------------------
__global__ __launch_bounds__(256)
void swizzle_split(const float* __restrict__ src, u16* __restrict__ hi,
                   u16* __restrict__ lo, int R, int DIN)
{
    __shared__ __align__(16) u16 SH[2][24][17][8];   // [plane][kc][row(pad)][8]
    const int tid  = threadIdx.x;
    const int row0 = blockIdx.x * 16;
    const int QK   = DIN / 16;          // float4 slots per row per quarter
    const int kq0  = QK * blockIdx.y;   // float4 offset of this quarter
    const int NKC  = DIN / 32;          // 16B k-chunks per quarter (<=24)

    const int slots = 16 * QK;
    for (int s = tid; s < slots; s += 256) {
        int row = s / QK, kq = s % QK;
        float4 v = *(const float4*)(src + (long)(row0 + row) * DIN + (long)(kq0 + kq) * 4);
        int kc = kq >> 1, jh = (kq & 1) * 4;
        float vv[4] = {v.x, v.y, v.z, v.w};
        u16x4v h, l;
#pragma unroll
        for (int j = 0; j < 4; ++j) {
            u16 hb = f2bf(vv[j]);
            h[j] = hb;
            l[j] = f2bf(vv[j] - bf2f(hb));
        }
        *(u16x4v*)(&SH[0][kc][row][jh]) = h;
        *(u16x4v*)(&SH[1][kc][row][jh]) = l;
    }
    __syncthreads();
    const int chunks = NKC * 16;
    for (int s = tid; s < chunks; s += 256) {
        int row = s & 15, kc = s >> 4;
        long o = ((long)(kq0 / 2 + kc) * R + row0 + row) * 8;
        *(u16x8v*)(hi + o) = *(const u16x8v*)(&SH[0][kc][row][0]);
        *(u16x8v*)(lo + o) = *(const u16x8v*)(&SH[1][kc][row][0]);
    }
}

// ---------------------------------------------------------------------------
// Shared epilogue: bias + LayerNorm + affine + relu, then store.
// OUT_MODE: 1 = split hi/lo bf16 swizzled global, 2 = LDS tile [64][129].
// NW = waves per block, TROWS = 32-row tiles per wave, NT = 32-col tiles.
// C/D layout: col=lane&31, row=(reg&3)+8*(reg>>2)+4*(lane>>5)  [m74/m101].
// ---------------------------------------------------------------------------
template<int DOUT, int OUT_MODE, int NT, int TROWS, int NW>
__device__ __forceinline__ void ln_epilogue(
    f32x16 (&acc)[TROWS][NT], float (&lnp)[NW][TROWS * 32][2],
    const float* __restrict__ bias, const float* __restrict__ gam,
    const float* __restrict__ bet,
    u16* __restrict__ Yh, u16* __restrict__ Yl, float* __restrict__ Yf,
    float* __restrict__ Hlds,
    long row0, int NR, int wv, int l31, int hh)
{
    float gg[NT], bb[NT], bev[NT];
#pragma unroll
    for (int u = 0; u < NT; ++u) {
        int c = wv * (NT * 32) + u * 32 + l31;
        bb[u] = bias[c]; gg[u] = gam[c]; bev[u] = bet[c];
    }
#pragma unroll
    for (int t = 0; t < TROWS; ++t)
#pragma unroll
        for (int r = 0; r < 16; ++r) {
            float s1 = 0.f, s2 = 0.f;
#pragma unroll
            for (int u = 0; u < NT; ++u) {
                float v = acc[t][u][r] + bb[u];
                acc[t][u][r] = v;
                s1 += v; s2 += v * v;
            }
#pragma unroll
            for (int off = 1; off < 32; off <<= 1) {
                s1 += __shfl_xor(s1, off, 64);
                s2 += __shfl_xor(s2, off, 64);
            }
            int row = t * 32 + (r & 3) + 8 * (r >> 2) + 4 * hh;
            if (l31 == r) { lnp[wv][row][0] = s1; lnp[wv][row][1] = s2; }
        }
    __syncthreads();
#pragma unroll
    for (int t = 0; t < TROWS; ++t)
#pragma unroll
        for (int r = 0; r < 16; ++r) {
            int row = t * 32 + (r & 3) + 8 * (r >> 2) + 4 * hh;
            float s1 = 0.f, s2 = 0.f;
#pragma unroll
            for (int w = 0; w < NW; ++w) { s1 += lnp[w][row][0]; s2 += lnp[w][row][1]; }
            float mean = s1 * (1.f / DOUT);
            float inv  = rsqrtf(s2 * (1.f / DOUT) - mean * mean + LN_EPS);
            long gr = row0 + row;
#pragma unroll
            for (int u = 0; u < NT; ++u) {
                int c = wv * (NT * 32) + u * 32 + l31;
                float v = (acc[t][u][r] - mean) * inv * gg[u] + bev[u];
                v = fmaxf(v, 0.f);
                if constexpr (OUT_MODE == 1) {
                    u16 hv = f2bf(v);
                    long o = ((long)(c >> 3) * NR + gr) * 8 + (c & 7);
                    Yh[o] = hv;
                    Yl[o] = f2bf(v - bf2f(hv));
                } else if constexpr (OUT_MODE == 2) {
                    Hlds[row * 129 + c] = v;
                } else {
                    Yf[gr * DOUT + c] = v;
                }
            }
        }
}

// ---------------------------------------------------------------------------
// One serial k-step: load W frags (global, L2-hot) then MFMA consume.
// chain-position-outer: TROWS*NT independent acc chains between dependent
// uses; per-acc order unchanged -> bit-identical numerics.
// W-load : MFMA ratio = 2NT : 3*TROWS*NT — TROWS=4 halves the W-wait
// frequency per MFMA vs TROWS=2 (round-9 post-mortem lever).
// ---------------------------------------------------------------------------
template<int NT, int TROWS>
__device__ __forceinline__ void mfma_step(
    const u16*& wph, const u16*& wpl, long wstep,
    const u16* AL0, const u16* AL1,   // chunk=hh base for plane0/plane1
    f32x16 (&acc)[TROWS][NT], int l31)
{
    bf16x8 wf[NT][2], af[TROWS][2];
#pragma unroll
    for (int u = 0; u < NT; ++u) {
        wf[u][0] = *(const bf16x8*)(wph + u * 256);
        wf[u][1] = *(const bf16x8*)(wpl + u * 256);
    }
    wph += wstep; wpl += wstep;
#pragma unroll
    for (int t = 0; t < TROWS; ++t) {
        af[t][0] = *(const bf16x8*)(AL0 + (t * 32 + l31) * 8);
        af[t][1] = *(const bf16x8*)(AL1 + (t * 32 + l31) * 8);
    }
#pragma unroll
    for (int t = 0; t < TROWS; ++t)
#pragma unroll
        for (int u = 0; u < NT; ++u)
            acc[t][u] = __builtin_amdgcn_mfma_f32_32x32x16_bf16(af[t][0], wf[u][0], acc[t][u], 0, 0, 0);
#pragma unroll
    for (int t = 0; t < TROWS; ++t)
#pragma unroll
        for (int u = 0; u < NT; ++u)
            acc[t][u] = __builtin_amdgcn_mfma_f32_32x32x16_bf16(af[t][0], wf[u][1], acc[t][u], 0, 0, 0);
#pragma unroll
    for (int t = 0; t < TROWS; ++t)
#pragma unroll
        for (int u = 0; u < NT; ++u)
            acc[t][u] = __builtin_amdgcn_mfma_f32_32x32x16_bf16(af[t][1], wf[u][0], acc[t][u], 0, 0, 0);
}

// ---------------------------------------------------------------------------
// Layer 1, 128-row blocks, 512 threads (8 waves): fp32 X input, fused split
// staging (16 fp32/thread). Wave = 128 rows x 64 cols: acc[4][2]=128 AGPR.
// ---------------------------------------------------------------------------
template<int DOUT>
__global__ __launch_bounds__(512, 2)
void mfma_layer1_b128(const float* __restrict__ X,
                      const u16* __restrict__ Wh, const u16* __restrict__ Wl,
                      const float* __restrict__ bias, const float* __restrict__ gam,
                      const float* __restrict__ bet,
                      u16* __restrict__ Yh, u16* __restrict__ Yl,
                      int DIN, int NR, long rbase)
{
    constexpr int NT = DOUT / 256;   // 2
    constexpr int TROWS = 4;
    // [buf][step][plane][chunk][128 rows * 8 + pad]
    __shared__ __align__(16) u16 AL[2][4][2][2][1040];
    __shared__ float lnp[8][128][2];

    const int tid  = threadIdx.x;
    const int lane = tid & 63, wv = tid >> 6;
    const int l31  = lane & 31, hh = lane >> 5;
    const long lrow0 = (long)blockIdx.x * 128;
    const long row0  = rbase + lrow0;

    const int srow  = tid >> 2;                    // 0..127
    const int kpart = tid & 3;                     // 16 fp32 each
    const float* xp = X + (lrow0 + srow) * DIN + kpart * 16;

    const u16* wph = Wh + ((long)hh * DOUT + wv * (NT * 32) + l31) * 8;
    const u16* wpl = Wl + ((long)hh * DOUT + wv * (NT * 32) + l31) * 8;
    const long wstep = (long)2 * DOUT * 8;

    f32x16 acc[TROWS][NT];
#pragma unroll
    for (int t = 0; t < TROWS; ++t)
#pragma unroll
        for (int u = 0; u < NT; ++u)
#pragma unroll
            for (int e = 0; e < 16; ++e) acc[t][u][e] = 0.f;

    const int nslab = DIN / 64;

    auto stage = [&](const float* p, int buf) {
#pragma unroll
        for (int c = 0; c < 2; ++c) {
            float4 v0 = *(const float4*)(p + c * 8);
            float4 v1 = *(const float4*)(p + c * 8 + 4);
            float f[8] = {v0.x, v0.y, v0.z, v0.w, v1.x, v1.y, v1.z, v1.w};
            u16x8v h, l;
#pragma unroll
            for (int j = 0; j < 8; ++j) {
                u16 hb = f2bf(f[j]);
                h[j] = hb;
                l[j] = f2bf(f[j] - bf2f(hb));
            }
            *(u16x8v*)(&AL[buf][kpart][0][c][srow * 8]) = h;
            *(u16x8v*)(&AL[buf][kpart][1][c][srow * 8]) = l;
        }
    };

    stage(xp, 0);                                   // prologue: slab 0
    for (int sl = 0; sl < nslab; ++sl) {
        __syncthreads();
        const int cb = sl & 1;
        if (sl + 1 < nslab) stage(xp + (sl + 1) * 64, cb ^ 1);
#pragma unroll
        for (int s = 0; s < 4; ++s)
            mfma_step<NT, TROWS>(wph, wpl, wstep,
                                 &AL[cb][s][0][hh][0], &AL[cb][s][1][hh][0],
                                 acc, l31);
    }

    ln_epilogue<DOUT, 1, NT, TROWS, 8>(acc, lnp, bias, gam, bet, Yh, Yl,
                                       nullptr, nullptr, row0, NR, wv, l31, hh);
}

// ---------------------------------------------------------------------------
// Layer 2, 128-row blocks, 512 threads (8 waves): pre-swizzled hi/lo bf16 A
// via GLD16 slab double-buffer (4 calls/wave/slab).
// ---------------------------------------------------------------------------
template<int DOUT>
__global__ __launch_bounds__(512, 2)
void mfma_layer_b128(const u16* __restrict__ Ah, const u16* __restrict__ Al,
                     const u16* __restrict__ Wh, const u16* __restrict__ Wl,
                     const float* __restrict__ bias, const float* __restrict__ gam,
                     const float* __restrict__ bet,
                     u16* __restrict__ Yh, u16* __restrict__ Yl,
                     int DIN, int NR)
{
    constexpr int NT = DOUT / 256;   // 2
    constexpr int TROWS = 4;
    // [buf][step][plane][chunk][128*8] — contiguous 2KB per slot for GLD16
    __shared__ __align__(16) u16 AL[2][4][2][2][1024];
    __shared__ float lnp[8][128][2];

    const int tid  = threadIdx.x;
    const int lane = tid & 63, wv = tid >> 6;
    const int l31  = lane & 31, hh = lane >> 5;
    const long row0 = (long)blockIdx.x * 128;

    // staging: 32 GLD16 calls/slab, 4 per wave. call i = wv*4+j:
    // s=i>>3, p=(i>>2)&1, c=(i>>1)&1, half=i&1; kc = slab*8 + s*2 + c.
    const u16* gp[4];
    int sj[4], pj[4], cj[4], hj[4];
#pragma unroll
    for (int j = 0; j < 4; ++j) {
        int i = wv * 4 + j;
        sj[j] = i >> 3; pj[j] = (i >> 2) & 1; cj[j] = (i >> 1) & 1; hj[j] = i & 1;
        const u16* base = pj[j] ? Al : Ah;
        gp[j] = base + ((long)(sj[j] * 2 + cj[j]) * NR + row0 + hj[j] * 64 + lane) * 8;
    }
    const long stA = (long)8 * NR * 8;

    const u16* wph = Wh + ((long)hh * DOUT + wv * (NT * 32) + l31) * 8;
    const u16* wpl = Wl + ((long)hh * DOUT + wv * (NT * 32) + l31) * 8;
    const long wstep = (long)2 * DOUT * 8;

    f32x16 acc[TROWS][NT];
#pragma unroll
    for (int t = 0; t < TROWS; ++t)
#pragma unroll
        for (int u = 0; u < NT; ++u)
#pragma unroll
            for (int e = 0; e < 16; ++e) acc[t][u][e] = 0.f;

    const int nslab = DIN / 64;
#pragma unroll
    for (int j = 0; j < 4; ++j) {
        GLD16(gp[j], &AL[0][sj[j]][pj[j]][cj[j]][hj[j] * 512]);
        gp[j] += stA;
    }

    for (int sl = 0; sl < nslab; ++sl) {
        __syncthreads();
        const int cb = sl & 1;
        if (sl + 1 < nslab) {
#pragma unroll
            for (int j = 0; j < 4; ++j) {
                GLD16(gp[j], &AL[cb ^ 1][sj[j]][pj[j]][cj[j]][hj[j] * 512]);
                gp[j] += stA;
            }
        }
#pragma unroll
        for (int s = 0; s < 4; ++s)
            mfma_step<NT, TROWS>(wph, wpl, wstep,
                                 &AL[cb][s][0][hh][0], &AL[cb][s][1][hh][0],
                                 acc, l31);
    }

    ln_epilogue<DOUT, 1, NT, TROWS, 8>(acc, lnp, bias, gam, bet, Yh, Yl,
                                       nullptr, nullptr, row0, NR, wv, l31, hh);
}

// ---------------------------------------------------------------------------
// Layer 3 (+fused layer 4), 64-row blocks, 256 threads (round-3 measured
// structure): DOUT=128, acc[2][1]=32 AGPR. Hs aliases dead A-staging LDS.
// ---------------------------------------------------------------------------
template<int DOUT>
__global__ __launch_bounds__(256, 4)
void mfma_layer3(const u16* __restrict__ Ah, const u16* __restrict__ Al,
                 const u16* __restrict__ Wh, const u16* __restrict__ Wl,
                 const float* __restrict__ bias, const float* __restrict__ gam,
                 const float* __restrict__ bet,
                 float* __restrict__ Yf, int DIN, int NR,
                 const float* __restrict__ W4, const float* __restrict__ b4)
{
    constexpr int NT = DOUT / 128;   // 1
    constexpr int TROWS = 2;
    // padded to 33280 B >= 64*129*4 B so Hs can alias it
    __shared__ __align__(16) u16 AL[2][4][2][2][520];
    __shared__ float lnp[4][64][2];
    float* Hs = (float*)&AL[0][0][0][0][0];

    const int tid  = threadIdx.x;
    const int lane = tid & 63, wv = tid >> 6;
    const int l31  = lane & 31, hh = lane >> 5;
    const long row0 = (long)blockIdx.x * 64;

    const u16* gpA[4];
    const long stA = (long)8 * NR * 8;
#pragma unroll
    for (int t = 0; t < 4; ++t) {
        int p = t & 1, c = t >> 1;
        const u16* base = p ? Al : Ah;
        gpA[t] = base + ((long)(2 * wv + c) * NR + row0 + lane) * 8;
    }

    const u16* wph = Wh + ((long)hh * DOUT + wv * (DOUT / 4) + l31) * 8;
    const u16* wpl = Wl + ((long)hh * DOUT + wv * (DOUT / 4) + l31) * 8;
    const long wstep = (long)2 * DOUT * 8;

    f32x16 acc[TROWS][NT];
#pragma unroll
    for (int t = 0; t < TROWS; ++t)
#pragma unroll
        for (int u = 0; u < NT; ++u)
#pragma unroll
            for (int e = 0; e < 16; ++e) acc[t][u][e] = 0.f;

    const int nslab = DIN / 64;
#pragma unroll
    for (int t = 0; t < 4; ++t) {
        GLD16(gpA[t], &AL[0][wv][t & 1][t >> 1][0]);
        gpA[t] += stA;
    }

    for (int sl = 0; sl < nslab; ++sl) {
        __syncthreads();
        const int cb = sl & 1;
        if (sl + 1 < nslab) {
#pragma unroll
            for (int t = 0; t < 4; ++t) {
                GLD16(gpA[t], &AL[cb ^ 1][wv][t & 1][t >> 1][0]);
                gpA[t] += stA;
            }
        }
#pragma unroll
        for (int s = 0; s < 4; ++s)
            mfma_step<NT, TROWS>(wph, wpl, wstep,
                                 &AL[cb][s][0][hh][0], &AL[cb][s][1][hh][0],
                                 acc, l31);
    }

    // epilogue phase 1 completes all AL reads before the sync inside;
    // phase 2 then overwrites AL via the Hs alias — safe.
    ln_epilogue<DOUT, 2, NT, TROWS, 4>(acc, lnp, bias, gam, bet, nullptr,
                                       nullptr, Yf, Hs, row0, NR, wv, l31, hh);

    // Fused layer 4: Z[row][o] = H[row][:] . W4[o][:] + b4[o]
    __syncthreads();
    const int rowl = tid & 63;
    const int og   = wv;            // 4 waves x 8 outputs = 32 cols
    float a4[8];
#pragma unroll
    for (int j = 0; j < 8; ++j) a4[j] = 0.f;
    for (int k = 0; k < 128; k += 4) {
        float h0 = Hs[rowl * 129 + k + 0];
        float h1 = Hs[rowl * 129 + k + 1];
        float h2 = Hs[rowl * 129 + k + 2];
        float h3 = Hs[rowl * 129 + k + 3];
#pragma unroll
        for (int j = 0; j < 8; ++j) {
            const float4 w = *(const float4*)(W4 + (og * 8 + j) * 128 + k);
            a4[j] = fmaf(h0, w.x, fmaf(h1, w.y, fmaf(h2, w.z, fmaf(h3, w.w, a4[j]))));
        }
    }
    const long gr = row0 + rowl;
#pragma unroll
    for (int j = 0; j < 8; ++j) Yf[gr * 32 + og * 8 + j] = a4[j] + b4[og * 8 + j];
}

// ---------------------------------------------------------------------------
// Prototypes: one block per class, no atomics.
// ---------------------------------------------------------------------------
__global__ __launch_bounds__(256)
void proto_k(const float* __restrict__ Zs, const int* __restrict__ lab,
             float* __restrict__ P)
{
    const int c = blockIdx.x;
    const int tid = threadIdx.x, lane = tid & 63, wv = tid >> 6;
    float acc[32];
#pragma unroll
    for (int d = 0; d < 32; ++d) acc[d] = 0.f;
    float cnt = 0.f;
    for (int i = tid; i < 32768; i += 256) {
        if (lab[i] == c) {
            cnt += 1.f;
#pragma unroll
            for (int d = 0; d < 32; ++d) acc[d] += Zs[(long)i * 32 + d];
        }
    }
    __shared__ float wsum[4][32];
    __shared__ float wcnt[4];
#pragma unroll
    for (int d = 0; d < 32; ++d) {
        float v = acc[d];
        for (int off = 32; off > 0; off >>= 1) v += __shfl_xor(v, off, 64);
        if (lane == 0) wsum[wv][d] = v;
    }
    {
        float v = cnt;
        for (int off = 32; off > 0; off >>= 1) v += __shfl_xor(v, off, 64);
        if (lane == 0) wcnt[wv] = v;
    }
    __syncthreads();
    if (tid < 32) {
        float s  = wsum[0][tid] + wsum[1][tid] + wsum[2][tid] + wsum[3][tid];
        float cn = wcnt[0] + wcnt[1] + wcnt[2] + wcnt[3];
        P[c * 32 + tid] = s / fmaxf(cn, 1.f);
    }
}

// ---------------------------------------------------------------------------
// -cdist: one thread per query row, protos in LDS.
// ---------------------------------------------------------------------------
__global__ __launch_bounds__(256)
void dist_k(const float* __restrict__ Zq, const float* __restrict__ P,
            float* __restrict__ O)
{
    __shared__ float ps[64 * 32];
    __shared__ float pn[64];
    const int tid = threadIdx.x;
    for (int idx = tid; idx < 2048; idx += 256) ps[idx] = P[idx];
    __syncthreads();
    if (tid < 64) {
        float s = 0.f;
        for (int d = 0; d < 32; ++d) { float v = ps[tid * 32 + d]; s += v * v; }
        pn[tid] = s;
    }
    __syncthreads();

    long q = (long)blockIdx.x * 256 + tid;
    float zr[32];
#pragma unroll
    for (int d = 0; d < 32; d += 4) {
        float4 v = *(const float4*)(Zq + q * 32 + d);
        zr[d] = v.x; zr[d + 1] = v.y; zr[d + 2] = v.z; zr[d + 3] = v.w;
    }
    float zz = 0.f;
#pragma unroll
    for (int d = 0; d < 32; ++d) zz += zr[d] * zr[d];
    for (int p = 0; p < 64; ++p) {
        float dot = 0.f;
#pragma unroll
        for (int d = 0; d < 32; ++d) dot = fmaf(zr[d], ps[p * 32 + d], dot);
        float sq = zz + pn[p] - 2.f * dot;
        O[q * 64 + p] = -sqrtf(fmaxf(sq, 0.f));
    }
}

// ---------------------------------------------------------------------------
// Host side — single pass over all 98304 rows (fits 768 MiB workspace).
// ---------------------------------------------------------------------------
extern "C" void kernel_launch(void* const* d_in, const int* in_sizes, int n_in,
                              void* d_out, int out_size, void* d_ws, size_t ws_size,
                              hipStream_t stream)
{
    const float* supp = (const float*)d_in[0];   // [32768,768]
    const int*   lab  = (const int*)  d_in[1];   // [32768]
    const float* qry  = (const float*)d_in[2];   // [65536,768]
    const float* W1 = (const float*)d_in[3];  const float* b1 = (const float*)d_in[4];
    const float* g1 = (const float*)d_in[5];  const float* be1= (const float*)d_in[6];
    const float* W2 = (const float*)d_in[7];  const float* b2 = (const float*)d_in[8];
    const float* g2 = (const float*)d_in[9];  const float* be2= (const float*)d_in[10];
    const float* W3 = (const float*)d_in[11]; const float* b3 = (const float*)d_in[12];
    const float* g3 = (const float*)d_in[13]; const float* be3= (const float*)d_in[14];
    const float* W4 = (const float*)d_in[15]; const float* b4 = (const float*)d_in[16];
    float* out = (float*)d_out;                  // [65536,64]

    const long NTOT = 98304, NS = 32768, NQ = 65536;
    const int  NR = (int)NTOT;

    char* wsp = (char*)d_ws;
    size_t off = 0;
    auto take = [&](size_t bytes) {
        char* p = wsp + off;
        off += (bytes + 255) & ~(size_t)255;
        return (void*)p;
    };

    float* zAll  = (float*)take((size_t)NTOT * 32 * 4);
    float* proto = (float*)take(2048 * 4);
    u16* W1h = (u16*)take((size_t)512 * 768 * 2);
    u16* W1l = (u16*)take((size_t)512 * 768 * 2);
    u16* W2h = (u16*)take((size_t)512 * 512 * 2);
    u16* W2l = (u16*)take((size_t)512 * 512 * 2);
    u16* W3h = (u16*)take((size_t)128 * 512 * 2);
    u16* W3l = (u16*)take((size_t)128 * 512 * 2);
    u16* h1h = (u16*)take((size_t)NTOT * 512 * 2);
    u16* h1l = (u16*)take((size_t)NTOT * 512 * 2);
    u16* h2h = (u16*)take((size_t)NTOT * 512 * 2);
    u16* h2l = (u16*)take((size_t)NTOT * 512 * 2);
    // total ~418 MB <= 768 MiB ws

    // split+swizzle weights (tiny)
    swizzle_split<<<dim3(32, 4), dim3(256), 0, stream>>>(W1, W1h, W1l, 512, 768);
    swizzle_split<<<dim3(32, 4), dim3(256), 0, stream>>>(W2, W2h, W2l, 512, 512);
    swizzle_split<<<dim3(8, 4),  dim3(256), 0, stream>>>(W3, W3h, W3l, 128, 512);

    // layer 1: fused fp32->split staging; two dispatches (support, query)
    mfma_layer1_b128<512><<<dim3(NS / 128), dim3(512), 0, stream>>>(
        supp, W1h, W1l, b1, g1, be1, h1h, h1l, 768, NR, 0);
    mfma_layer1_b128<512><<<dim3(NQ / 128), dim3(512), 0, stream>>>(
        qry, W1h, W1l, b1, g1, be1, h1h, h1l, 768, NR, NS);

    mfma_layer_b128<512><<<dim3(NTOT / 128), dim3(512), 0, stream>>>(
        h1h, h1l, W2h, W2l, b2, g2, be2, h2h, h2l, 512, NR);
    // layer 3 with fused layer 4: writes zAll directly (no h3 round trip)
    mfma_layer3<128><<<dim3(NTOT / 64), dim3(256), 0, stream>>>(
        h2h, h2l, W3h, W3l, b3, g3, be3, zAll, 512, NR, W4, b4);

    proto_k<<<dim3(64),  dim3(256), 0, stream>>>(zAll, lab, proto);
    dist_k<<<dim3(256), dim3(256), 0, stream>>>(zAll + NS * 32, proto, out);
}

// Round 15
// 1008.725 us; speedup vs baseline: 1.1361x; 1.0819x over previous
//
#include <hip/hip_runtime.h>

typedef unsigned short u16;
typedef short bf16x8 __attribute__((ext_vector_type(8)));
typedef float f32x16 __attribute__((ext_vector_type(16)));
typedef unsigned short u16x4v __attribute__((ext_vector_type(4)));
typedef unsigned short u16x8v __attribute__((ext_vector_type(8)));

#define LN_EPS 1e-5f

__device__ __forceinline__ u16 f2bf(float v) {
    unsigned x = __float_as_uint(v);
    x += 0x7fffu + ((x >> 16) & 1u);        // RNE to bf16
    return (u16)(x >> 16);
}
__device__ __forceinline__ float bf2f(u16 u) {
    return __uint_as_float(((unsigned)u) << 16);
}

#define GLD16(gp, lp) __builtin_amdgcn_global_load_lds( \
    (const __attribute__((address_space(1))) void*)(gp), \
    (__attribute__((address_space(3))) void*)(lp), 16, 0, 0)

#define SB0 __builtin_amdgcn_sched_barrier(0)

// ---------------------------------------------------------------------------
// fp32 [R][DIN] row-major -> hi/lo bf16 planes, MFMA-staging layout
// [DIN/8][R][8]. Used for WEIGHTS only (tiny).
// ---------------------------------------------------------------------------
__global__ __launch_bounds__(256)
void swizzle_split(const float* __restrict__ src, u16* __restrict__ hi,
                   u16* __restrict__ lo, int R, int DIN)
{
    __shared__ __align__(16) u16 SH[2][24][17][8];   // [plane][kc][row(pad)][8]
    const int tid  = threadIdx.x;
    const int row0 = blockIdx.x * 16;
    const int QK   = DIN / 16;          // float4 slots per row per quarter
    const int kq0  = QK * blockIdx.y;   // float4 offset of this quarter
    const int NKC  = DIN / 32;          // 16B k-chunks per quarter (<=24)

    const int slots = 16 * QK;
    for (int s = tid; s < slots; s += 256) {
        int row = s / QK, kq = s % QK;
        float4 v = *(const float4*)(src + (long)(row0 + row) * DIN + (long)(kq0 + kq) * 4);
        int kc = kq >> 1, jh = (kq & 1) * 4;
        float vv[4] = {v.x, v.y, v.z, v.w};
        u16x4v h, l;
#pragma unroll
        for (int j = 0; j < 4; ++j) {
            u16 hb = f2bf(vv[j]);
            h[j] = hb;
            l[j] = f2bf(vv[j] - bf2f(hb));
        }
        *(u16x4v*)(&SH[0][kc][row][jh]) = h;
        *(u16x4v*)(&SH[1][kc][row][jh]) = l;
    }
    __syncthreads();
    const int chunks = NKC * 16;
    for (int s = tid; s < chunks; s += 256) {
        int row = s & 15, kc = s >> 4;
        long o = ((long)(kq0 / 2 + kc) * R + row0 + row) * 8;
        *(u16x8v*)(hi + o) = *(const u16x8v*)(&SH[0][kc][row][0]);
        *(u16x8v*)(lo + o) = *(const u16x8v*)(&SH[1][kc][row][0]);
    }
}

// ---------------------------------------------------------------------------
// Shared epilogue: bias + LayerNorm + affine + relu, then store.
// OUT_MODE: 1 = split hi/lo bf16 swizzled global, 2 = LDS tile [64][129].
// C/D layout: col=lane&31, row=(reg&3)+8*(reg>>2)+4*(lane>>5)  [m74/m101].
// ---------------------------------------------------------------------------
template<int DOUT, int OUT_MODE, int NT>
__device__ __forceinline__ void ln_epilogue(
    f32x16 (&acc)[2][NT], float (&lnp)[4][64][2],
    const float* __restrict__ bias, const float* __restrict__ gam,
    const float* __restrict__ bet,
    u16* __restrict__ Yh, u16* __restrict__ Yl, float* __restrict__ Yf,
    float* __restrict__ Hlds,
    long row0, int NR, int wv, int l31, int hh)
{
    float gg[NT], bb[NT], bev[NT];
#pragma unroll
    for (int u = 0; u < NT; ++u) {
        int c = wv * (DOUT / 4) + u * 32 + l31;
        bb[u] = bias[c]; gg[u] = gam[c]; bev[u] = bet[c];
    }
#pragma unroll
    for (int t = 0; t < 2; ++t)
#pragma unroll
        for (int r = 0; r < 16; ++r) {
            float s1 = 0.f, s2 = 0.f;
#pragma unroll
            for (int u = 0; u < NT; ++u) {
                float v = acc[t][u][r] + bb[u];
                acc[t][u][r] = v;
                s1 += v; s2 += v * v;
            }
#pragma unroll
            for (int off = 1; off < 32; off <<= 1) {
                s1 += __shfl_xor(s1, off, 64);
                s2 += __shfl_xor(s2, off, 64);
            }
            int row = t * 32 + (r & 3) + 8 * (r >> 2) + 4 * hh;
            if (l31 == r) { lnp[wv][row][0] = s1; lnp[wv][row][1] = s2; }
        }
    __syncthreads();
#pragma unroll
    for (int t = 0; t < 2; ++t)
#pragma unroll
        for (int r = 0; r < 16; ++r) {
            int row = t * 32 + (r & 3) + 8 * (r >> 2) + 4 * hh;
            float s1 = lnp[0][row][0] + lnp[1][row][0] + lnp[2][row][0] + lnp[3][row][0];
            float s2 = lnp[0][row][1] + lnp[1][row][1] + lnp[2][row][1] + lnp[3][row][1];
            float mean = s1 * (1.f / DOUT);
            float inv  = rsqrtf(s2 * (1.f / DOUT) - mean * mean + LN_EPS);
            long gr = row0 + row;
#pragma unroll
            for (int u = 0; u < NT; ++u) {
                int c = wv * (DOUT / 4) + u * 32 + l31;
                float v = (acc[t][u][r] - mean) * inv * gg[u] + bev[u];
                v = fmaxf(v, 0.f);
                if constexpr (OUT_MODE == 1) {
                    u16 hv = f2bf(v);
                    long o = ((long)(c >> 3) * NR + gr) * 8 + (c & 7);
                    Yh[o] = hv;
                    Yl[o] = f2bf(v - bf2f(hv));
                } else if constexpr (OUT_MODE == 2) {
                    Hlds[row * 129 + c] = v;
                } else {
                    Yf[gr * DOUT + c] = v;
                }
            }
        }
}

// ---------------------------------------------------------------------------
// W-fragment load / MFMA-consume helpers (no fences inside).
// chain-position-outer MFMA order: 2*NT independent acc chains between
// dependent uses; per-acc order unchanged -> bit-identical numerics.
// ---------------------------------------------------------------------------
template<int NT>
__device__ __forceinline__ void ldwf(const u16*& wph, const u16*& wpl,
                                     long wstep, bf16x8 (&wf)[NT][2])
{
#pragma unroll
    for (int u = 0; u < NT; ++u) {
        wf[u][0] = *(const bf16x8*)(wph + u * 256);
        wf[u][1] = *(const bf16x8*)(wpl + u * 256);
    }
    wph += wstep; wpl += wstep;
}

template<int NT>
__device__ __forceinline__ void mfma_use(
    const bf16x8 (&wf)[NT][2],
    const u16* AL0, const u16* AL1,   // chunk=hh base for plane0/plane1
    f32x16 (&acc)[2][NT], int l31)
{
    bf16x8 af[2][2];
#pragma unroll
    for (int t = 0; t < 2; ++t) {
        af[t][0] = *(const bf16x8*)(AL0 + (t * 32 + l31) * 8);
        af[t][1] = *(const bf16x8*)(AL1 + (t * 32 + l31) * 8);
    }
#pragma unroll
    for (int t = 0; t < 2; ++t)
#pragma unroll
        for (int u = 0; u < NT; ++u)
            acc[t][u] = __builtin_amdgcn_mfma_f32_32x32x16_bf16(af[t][0], wf[u][0], acc[t][u], 0, 0, 0);
#pragma unroll
    for (int t = 0; t < 2; ++t)
#pragma unroll
        for (int u = 0; u < NT; ++u)
            acc[t][u] = __builtin_amdgcn_mfma_f32_32x32x16_bf16(af[t][0], wf[u][1], acc[t][u], 0, 0, 0);
#pragma unroll
    for (int t = 0; t < 2; ++t)
#pragma unroll
        for (int u = 0; u < NT; ++u)
            acc[t][u] = __builtin_amdgcn_mfma_f32_32x32x16_bf16(af[t][1], wf[u][0], acc[t][u], 0, 0, 0);
}

// fused load+use (steps 1..3 — identical to round-3 mfma_step)
template<int NT>
__device__ __forceinline__ void mfma_step(
    const u16*& wph, const u16*& wpl, long wstep,
    const u16* AL0, const u16* AL1,
    f32x16 (&acc)[2][NT], int l31)
{
    bf16x8 wf[NT][2];
    ldwf<NT>(wph, wpl, wstep, wf);
    mfma_use<NT>(wf, AL0, AL1, acc, l31);
}

// ---------------------------------------------------------------------------
// Layer 1, 64-row blocks (exact round-3 structure, best measured).
// ---------------------------------------------------------------------------
template<int DOUT>
__global__ __launch_bounds__(256, 2)
void mfma_layer1(const float* __restrict__ X,
                 const u16* __restrict__ Wh, const u16* __restrict__ Wl,
                 const float* __restrict__ bias, const float* __restrict__ gam,
                 const float* __restrict__ bet,
                 u16* __restrict__ Yh, u16* __restrict__ Yl,
                 int DIN, int NR, long rbase)
{
    constexpr int NT = DOUT / 128;
    __shared__ __align__(16) u16 AL[2][4][2][2][520]; // [buf][step][plane][chunk][pad]
    __shared__ float lnp[4][64][2];

    const int tid  = threadIdx.x;
    const int lane = tid & 63, wv = tid >> 6;
    const int l31  = lane & 31, hh = lane >> 5;
    const long lrow0 = (long)blockIdx.x * 64;
    const long row0  = rbase + lrow0;

    const int srow  = wv * 16 + (lane >> 2);       // staging row this thread owns
    const int kpart = lane & 3;                    // which 16-k step it stages
    const float* xp = X + (lrow0 + srow) * DIN + kpart * 16;

    const u16* wph = Wh + ((long)hh * DOUT + wv * (DOUT / 4) + l31) * 8;
    const u16* wpl = Wl + ((long)hh * DOUT + wv * (DOUT / 4) + l31) * 8;
    const long wstep = (long)2 * DOUT * 8;

    f32x16 acc[2][NT];
#pragma unroll
    for (int t = 0; t < 2; ++t)
#pragma unroll
        for (int u = 0; u < NT; ++u)
#pragma unroll
            for (int e = 0; e < 16; ++e) acc[t][u][e] = 0.f;

    const int nslab = DIN / 64;

    auto stage = [&](const float* p, int buf) {
#pragma unroll
        for (int c = 0; c < 2; ++c) {
            float4 v0 = *(const float4*)(p + c * 8);
            float4 v1 = *(const float4*)(p + c * 8 + 4);
            float f[8] = {v0.x, v0.y, v0.z, v0.w, v1.x, v1.y, v1.z, v1.w};
            u16x8v h, l;
#pragma unroll
            for (int j = 0; j < 8; ++j) {
                u16 hb = f2bf(f[j]);
                h[j] = hb;
                l[j] = f2bf(f[j] - bf2f(hb));
            }
            *(u16x8v*)(&AL[buf][kpart][0][c][srow * 8]) = h;
            *(u16x8v*)(&AL[buf][kpart][1][c][srow * 8]) = l;
        }
    };

    stage(xp, 0);                                   // prologue: slab 0
    for (int sl = 0; sl < nslab; ++sl) {
        __syncthreads();
        const int cb = sl & 1;
        if (sl + 1 < nslab) stage(xp + (sl + 1) * 64, cb ^ 1);
#pragma unroll
        for (int s = 0; s < 4; ++s) {
            mfma_step<NT>(wph, wpl, wstep,
                          &AL[cb][s][0][hh][0], &AL[cb][s][1][hh][0],
                          acc, l31);
        }
    }

    ln_epilogue<DOUT, 1, NT>(acc, lnp, bias, gam, bet, Yh, Yl, nullptr, nullptr,
                             row0, NR, wv, l31, hh);
}

// ---------------------------------------------------------------------------
// Layers 2/3, 64-row blocks. ONE change vs round-3: per slab, step-0's W
// loads are issued BEFORE the GLD16 A-prefetch (SB0-pinned). vmcnt retires
// in issue order, so step-0's W wait becomes a COUNTED vmcnt(4) — the HBM
// prefetch stays in flight under step-0's MFMA burst instead of being
// drained at the W wait (the per-slab ~900cy stall in the old order).
// OUT_MODE==2 fuses layer 4 via the Hs LDS tile.
// ---------------------------------------------------------------------------
template<int DOUT, int OUT_MODE>
__global__ __launch_bounds__(256, 2)
void mfma_layer(const u16* __restrict__ Ah, const u16* __restrict__ Al,
                const u16* __restrict__ Wh, const u16* __restrict__ Wl,
                const float* __restrict__ bias, const float* __restrict__ gam,
                const float* __restrict__ bet,
                u16* __restrict__ Yh, u16* __restrict__ Yl,
                float* __restrict__ Yf, int DIN, int NR,
                const float* __restrict__ W4, const float* __restrict__ b4)
{
    constexpr int NT = DOUT / 128;
    __shared__ __align__(16) u16 AL[2][4][2][2][64 * 8];
    __shared__ float lnp[4][64][2];
    // layer-4 fusion tile: [64][129] fp32; stride 129 -> bank=(row+col)%32,
    // conflict-free both directions. 1-elem dummy otherwise.
    __shared__ float Hs[OUT_MODE == 2 ? 64 * 129 : 1];

    const int tid  = threadIdx.x;
    const int lane = tid & 63, wv = tid >> 6;
    const int l31  = lane & 31, hh = lane >> 5;
    const long row0 = (long)blockIdx.x * 64;

    const u16* gpA[4];
    const long stA = (long)8 * NR * 8;
#pragma unroll
    for (int t = 0; t < 4; ++t) {
        int p = t & 1, c = t >> 1;
        const u16* base = p ? Al : Ah;
        gpA[t] = base + ((long)(2 * wv + c) * NR + row0 + lane) * 8;
    }

    const u16* wph = Wh + ((long)hh * DOUT + wv * (DOUT / 4) + l31) * 8;
    const u16* wpl = Wl + ((long)hh * DOUT + wv * (DOUT / 4) + l31) * 8;
    const long wstep = (long)2 * DOUT * 8;

    f32x16 acc[2][NT];
#pragma unroll
    for (int t = 0; t < 2; ++t)
#pragma unroll
        for (int u = 0; u < NT; ++u)
#pragma unroll
            for (int e = 0; e < 16; ++e) acc[t][u][e] = 0.f;

    const int nslab = DIN / 64;
#pragma unroll
    for (int t = 0; t < 4; ++t) {
        GLD16(gpA[t], &AL[0][wv][t & 1][t >> 1][0]);
        gpA[t] += stA;
    }

    for (int sl = 0; sl < nslab; ++sl) {
        __syncthreads();
        const int cb = sl & 1;

        // --- step 0, reordered: W loads first, then A-prefetch, then MFMA.
        bf16x8 wf0[NT][2];
        ldwf<NT>(wph, wpl, wstep, wf0);
        SB0;                                   // pin: wf0 loads issue first
        if (sl + 1 < nslab) {
#pragma unroll
            for (int t = 0; t < 4; ++t) {
                GLD16(gpA[t], &AL[cb ^ 1][wv][t & 1][t >> 1][0]);
                gpA[t] += stA;
            }
        }
        SB0;                                   // pin: GLD16s before consume
        mfma_use<NT>(wf0, &AL[cb][0][0][hh][0], &AL[cb][0][1][hh][0], acc, l31);

        // --- steps 1..3 unchanged (GLD16s retire under step-0 MFMAs).
#pragma unroll
        for (int s = 1; s < 4; ++s) {
            mfma_step<NT>(wph, wpl, wstep,
                          &AL[cb][s][0][hh][0], &AL[cb][s][1][hh][0],
                          acc, l31);
        }
    }

    ln_epilogue<DOUT, OUT_MODE, NT>(acc, lnp, bias, gam, bet, Yh, Yl, Yf, Hs,
                                    row0, NR, wv, l31, hh);

    if constexpr (OUT_MODE == 2) {
        // Fused layer 4: Z[row][o] = H[row][:] . W4[o][:] + b4[o]
        __syncthreads();
        const int rowl = tid & 63;
        const int og   = wv;            // 4 waves x 8 outputs = 32 cols
        float a4[8];
#pragma unroll
        for (int j = 0; j < 8; ++j) a4[j] = 0.f;
        for (int k = 0; k < 128; k += 4) {
            float h0 = Hs[rowl * 129 + k + 0];
            float h1 = Hs[rowl * 129 + k + 1];
            float h2 = Hs[rowl * 129 + k + 2];
            float h3 = Hs[rowl * 129 + k + 3];
#pragma unroll
            for (int j = 0; j < 8; ++j) {
                const float4 w = *(const float4*)(W4 + (og * 8 + j) * 128 + k);
                a4[j] = fmaf(h0, w.x, fmaf(h1, w.y, fmaf(h2, w.z, fmaf(h3, w.w, a4[j]))));
            }
        }
        const long gr = row0 + rowl;
#pragma unroll
        for (int j = 0; j < 8; ++j) Yf[gr * 32 + og * 8 + j] = a4[j] + b4[og * 8 + j];
    }
}

// ---------------------------------------------------------------------------
// Prototypes: one block per class, no atomics.
// ---------------------------------------------------------------------------
__global__ __launch_bounds__(256)
void proto_k(const float* __restrict__ Zs, const int* __restrict__ lab,
             float* __restrict__ P)
{
    const int c = blockIdx.x;
    const int tid = threadIdx.x, lane = tid & 63, wv = tid >> 6;
    float acc[32];
#pragma unroll
    for (int d = 0; d < 32; ++d) acc[d] = 0.f;
    float cnt = 0.f;
    for (int i = tid; i < 32768; i += 256) {
        if (lab[i] == c) {
            cnt += 1.f;
#pragma unroll
            for (int d = 0; d < 32; ++d) acc[d] += Zs[(long)i * 32 + d];
        }
    }
    __shared__ float wsum[4][32];
    __shared__ float wcnt[4];
#pragma unroll
    for (int d = 0; d < 32; ++d) {
        float v = acc[d];
        for (int off = 32; off > 0; off >>= 1) v += __shfl_xor(v, off, 64);
        if (lane == 0) wsum[wv][d] = v;
    }
    {
        float v = cnt;
        for (int off = 32; off > 0; off >>= 1) v += __shfl_xor(v, off, 64);
        if (lane == 0) wcnt[wv] = v;
    }
    __syncthreads();
    if (tid < 32) {
        float s  = wsum[0][tid] + wsum[1][tid] + wsum[2][tid] + wsum[3][tid];
        float cn = wcnt[0] + wcnt[1] + wcnt[2] + wcnt[3];
        P[c * 32 + tid] = s / fmaxf(cn, 1.f);
    }
}

// ---------------------------------------------------------------------------
// -cdist: one thread per query row, protos in LDS.
// ---------------------------------------------------------------------------
__global__ __launch_bounds__(256)
void dist_k(const float* __restrict__ Zq, const float* __restrict__ P,
            float* __restrict__ O)
{
    __shared__ float ps[64 * 32];
    __shared__ float pn[64];
    const int tid = threadIdx.x;
    for (int idx = tid; idx < 2048; idx += 256) ps[idx] = P[idx];
    __syncthreads();
    if (tid < 64) {
        float s = 0.f;
        for (int d = 0; d < 32; ++d) { float v = ps[tid * 32 + d]; s += v * v; }
        pn[tid] = s;
    }
    __syncthreads();

    long q = (long)blockIdx.x * 256 + tid;
    float zr[32];
#pragma unroll
    for (int d = 0; d < 32; d += 4) {
        float4 v = *(const float4*)(Zq + q * 32 + d);
        zr[d] = v.x; zr[d + 1] = v.y; zr[d + 2] = v.z; zr[d + 3] = v.w;
    }
    float zz = 0.f;
#pragma unroll
    for (int d = 0; d < 32; ++d) zz += zr[d] * zr[d];
    for (int p = 0; p < 64; ++p) {
        float dot = 0.f;
#pragma unroll
        for (int d = 0; d < 32; ++d) dot = fmaf(zr[d], ps[p * 32 + d], dot);
        float sq = zz + pn[p] - 2.f * dot;
        O[q * 64 + p] = -sqrtf(fmaxf(sq, 0.f));
    }
}

// ---------------------------------------------------------------------------
// Host side — single pass over all 98304 rows (fits 768 MiB workspace).
// ---------------------------------------------------------------------------
extern "C" void kernel_launch(void* const* d_in, const int* in_sizes, int n_in,
                              void* d_out, int out_size, void* d_ws, size_t ws_size,
                              hipStream_t stream)
{
    const float* supp = (const float*)d_in[0];   // [32768,768]
    const int*   lab  = (const int*)  d_in[1];   // [32768]
    const float* qry  = (const float*)d_in[2];   // [65536,768]
    const float* W1 = (const float*)d_in[3];  const float* b1 = (const float*)d_in[4];
    const float* g1 = (const float*)d_in[5];  const float* be1= (const float*)d_in[6];
    const float* W2 = (const float*)d_in[7];  const float* b2 = (const float*)d_in[8];
    const float* g2 = (const float*)d_in[9];  const float* be2= (const float*)d_in[10];
    const float* W3 = (const float*)d_in[11]; const float* b3 = (const float*)d_in[12];
    const float* g3 = (const float*)d_in[13]; const float* be3= (const float*)d_in[14];
    const float* W4 = (const float*)d_in[15]; const float* b4 = (const float*)d_in[16];
    float* out = (float*)d_out;                  // [65536,64]

    const long NTOT = 98304, NS = 32768, NQ = 65536;
    const int  NR = (int)NTOT;

    char* wsp = (char*)d_ws;
    size_t off = 0;
    auto take = [&](size_t bytes) {
        char* p = wsp + off;
        off += (bytes + 255) & ~(size_t)255;
        return (void*)p;
    };

    float* zAll  = (float*)take((size_t)NTOT * 32 * 4);
    float* proto = (float*)take(2048 * 4);
    u16* W1h = (u16*)take((size_t)512 * 768 * 2);
    u16* W1l = (u16*)take((size_t)512 * 768 * 2);
    u16* W2h = (u16*)take((size_t)512 * 512 * 2);
    u16* W2l = (u16*)take((size_t)512 * 512 * 2);
    u16* W3h = (u16*)take((size_t)128 * 512 * 2);
    u16* W3l = (u16*)take((size_t)128 * 512 * 2);
    u16* h1h = (u16*)take((size_t)NTOT * 512 * 2);
    u16* h1l = (u16*)take((size_t)NTOT * 512 * 2);
    u16* h2h = (u16*)take((size_t)NTOT * 512 * 2);
    u16* h2l = (u16*)take((size_t)NTOT * 512 * 2);
    // total ~418 MB <= 768 MiB ws

    // split+swizzle weights (tiny)
    swizzle_split<<<dim3(32, 4), dim3(256), 0, stream>>>(W1, W1h, W1l, 512, 768);
    swizzle_split<<<dim3(32, 4), dim3(256), 0, stream>>>(W2, W2h, W2l, 512, 512);
    swizzle_split<<<dim3(8, 4),  dim3(256), 0, stream>>>(W3, W3h, W3l, 128, 512);

    // layer 1: fused fp32->split staging; two dispatches (support, query)
    mfma_layer1<512><<<dim3(NS / 64), dim3(256), 0, stream>>>(
        supp, W1h, W1l, b1, g1, be1, h1h, h1l, 768, NR, 0);
    mfma_layer1<512><<<dim3(NQ / 64), dim3(256), 0, stream>>>(
        qry, W1h, W1l, b1, g1, be1, h1h, h1l, 768, NR, NS);

    mfma_layer<512, 1><<<dim3(NTOT / 64), dim3(256), 0, stream>>>(
        h1h, h1l, W2h, W2l, b2, g2, be2, h2h, h2l, nullptr, 512, NR,
        nullptr, nullptr);
    // layer 3 with fused layer 4: writes zAll directly (no h3 round trip)
    mfma_layer<128, 2><<<dim3(NTOT / 64), dim3(256), 0, stream>>>(
        h2h, h2l, W3h, W3l, b3, g3, be3, nullptr, nullptr, zAll, 512, NR,
        W4, b4);

    proto_k<<<dim3(64),  dim3(256), 0, stream>>>(zAll, lab, proto);
    dist_k<<<dim3(256), dim3(256), 0, stream>>>(zAll + NS * 32, proto, out);
}